// Round 4
// baseline (111.819 us; speedup 1.0000x reference)
//
#include <hip/hip_runtime.h>

// ZNCC 5x5, zero-padded, count_include_pad means.
// x,y: (4,3,512,512) f32 -> out: (4,1,512,512) f32
// Round 4: stage ALL 3 channels x {x,y} (6 tiles, 32.6KB) with ONE barrier,
// then barrier-free compute. 512-thread blocks, 2px/thread, 64x16 tile:
// 4 blocks/CU (LDS-capped) x 8 waves = 32 waves/CU (100% occupancy ceiling).

constexpr int W  = 512, H = 512, C = 3, NB = 4;
constexpr int TW = 64, TH = 16, HALO = 2;
constexpr int LW = TW + 2 * HALO;   // 68
constexpr int LH = TH + 2 * HALO;   // 20
constexpr int LSZ = LW * LH;        // 1360

__global__ __launch_bounds__(512, 8)
void zncc_kernel(const float* __restrict__ x,
                 const float* __restrict__ y,
                 float* __restrict__ out) {
    __shared__ float sm[6][LSZ];    // [c*2+0]=x, [c*2+1]=y ; 32640 B

    const int tid = threadIdx.x;
    const int tx  = tid & 31;    // 32 thread-cols x 2 px = 64 cols
    const int ty  = tid >> 5;    // 16 rows
    const int w0  = blockIdx.x * TW;
    const int h0  = blockIdx.y * TH;
    const int b   = blockIdx.z;

    const float EPS = 1e-4f;

    // ---- stage all 6 tiles, single barrier ----
    #pragma unroll
    for (int a = 0; a < 6; ++a) {
        const float* __restrict__ src =
            (a & 1 ? y : x) + (size_t)(b * C + (a >> 1)) * (H * W);
        float* dst = &sm[a][0];
        for (int i = tid; i < LSZ; i += 512) {
            const int l  = i / LW;
            const int m  = i - l * LW;
            const int gr = h0 + l - HALO;
            const int gc = w0 + m - HALO;
            const bool ok = ((unsigned)gr < (unsigned)H) && ((unsigned)gc < (unsigned)W);
            dst[i] = ok ? src[gr * W + gc] : 0.f;
        }
    }
    __syncthreads();

    float chan_acc[2] = {0.f, 0.f};

    for (int c = 0; c < C; ++c) {
        const float* bx = &sm[2 * c][0];
        const float* by = &sm[2 * c + 1][0];

        // ---- pass A: 5x5 sums for my 2 pixels ----
        float sx0 = 0.f, sx1 = 0.f, sy0 = 0.f, sy1 = 0.f;
        #pragma unroll
        for (int r = 0; r < 5; ++r) {
            const int base = (ty + r) * LW + 2 * tx;
            const float2 a0 = *reinterpret_cast<const float2*>(&bx[base]);
            const float2 a1 = *reinterpret_cast<const float2*>(&bx[base + 2]);
            const float2 a2 = *reinterpret_cast<const float2*>(&bx[base + 4]);
            const float2 b0 = *reinterpret_cast<const float2*>(&by[base]);
            const float2 b1 = *reinterpret_cast<const float2*>(&by[base + 2]);
            const float2 b2 = *reinterpret_cast<const float2*>(&by[base + 4]);
            const float cxm = a0.y + a1.x + a1.y + a2.x;   // shared middle 4
            sx0 += cxm + a0.x;
            sx1 += cxm + a2.y;
            const float cym = b0.y + b1.x + b1.y + b2.x;
            sy0 += cym + b0.x;
            sy1 += cym + b2.y;
        }
        const float mx0 = sx0 * (1.f / 25.f), mx1 = sx1 * (1.f / 25.f);
        const float my0 = sy0 * (1.f / 25.f), my1 = sy1 * (1.f / 25.f);

        // ---- pass B: ncc accumulation ----
        float acc0 = 0.f, acc1 = 0.f;
        #pragma unroll
        for (int r = 0; r < 5; ++r) {
            const int base = (ty + r) * LW + 2 * tx;
            const float2 a0 = *reinterpret_cast<const float2*>(&bx[base]);
            const float2 a1 = *reinterpret_cast<const float2*>(&bx[base + 2]);
            const float2 a2 = *reinterpret_cast<const float2*>(&bx[base + 4]);
            const float2 b0 = *reinterpret_cast<const float2*>(&by[base]);
            const float2 b1 = *reinterpret_cast<const float2*>(&by[base + 2]);
            const float2 b2 = *reinterpret_cast<const float2*>(&by[base + 4]);
            const float cx[6] = {a0.x, a0.y, a1.x, a1.y, a2.x, a2.y};
            const float cy[6] = {b0.x, b0.y, b1.x, b1.y, b2.x, b2.y};
            #pragma unroll
            for (int j = 0; j < 5; ++j) {
                {
                    const float dx  = cx[j] - mx0;
                    const float dy  = cy[j] - my0;
                    const float num = fabsf(dx * dy) + EPS;
                    const float den = (dx * dx + EPS) * (dy * dy + EPS);
                    acc0 += num * __builtin_amdgcn_rsqf(den);
                }
                {
                    const float dx  = cx[j + 1] - mx1;
                    const float dy  = cy[j + 1] - my1;
                    const float num = fabsf(dx * dy) + EPS;
                    const float den = (dx * dx + EPS) * (dy * dy + EPS);
                    acc1 += num * __builtin_amdgcn_rsqf(den);
                }
            }
        }
        float v0 = acc0 * (1.f / 25.f);
        float v1 = acc1 * (1.f / 25.f);
        v0 = fminf(fmaxf(v0, 0.f), 1.f);
        v1 = fminf(fmaxf(v1, 0.f), 1.f);
        chan_acc[0] += v0;
        chan_acc[1] += v1;
    }

    const int orow = h0 + ty;
    float2 o;
    o.x = chan_acc[0] * (1.f / 3.f);
    o.y = chan_acc[1] * (1.f / 3.f);
    *reinterpret_cast<float2*>(&out[((size_t)b * H + orow) * W + w0 + 2 * tx]) = o;
}

extern "C" void kernel_launch(void* const* d_in, const int* in_sizes, int n_in,
                              void* d_out, int out_size, void* d_ws, size_t ws_size,
                              hipStream_t stream) {
    const float* x = (const float*)d_in[0];
    const float* y = (const float*)d_in[1];
    float* out = (float*)d_out;
    dim3 grid(W / TW, H / TH, NB);   // 8, 32, 4 = 1024 blocks (4 per CU)
    zncc_kernel<<<grid, dim3(512), 0, stream>>>(x, y, out);
}

// Round 5
// 47.363 us; speedup vs baseline: 2.3609x; 2.3609x over previous
//
#include <hip/hip_runtime.h>

// ZNCC 5x5, zero-padded, count_include_pad means.
// x,y: (4,3,512,512) f32 -> out: (4,1,512,512) f32
// Round 5: channel parallelism across wave-groups. 768-thread blocks = three
// 256-thread groups; group g runs the round-1 two-pass body on channel g
// concurrently. One stage barrier + one reduce barrier per block.
// LDS 41KB -> 2 blocks/CU (L2 working set 2.6MB/XCD < 4MB; round-4 thrash avoided).

constexpr int W  = 512, H = 512, C = 3, NB = 4;
constexpr int TW = 64, TH = 16, HALO = 2;
constexpr int LW = TW + 2 * HALO;   // 68 (float4 alignment kept: 4*tx base, stride 272B)
constexpr int LH = TH + 2 * HALO;   // 20
constexpr int LSZ = LW * LH;        // 1360

__global__ __launch_bounds__(768, 6)
void zncc_kernel(const float* __restrict__ x,
                 const float* __restrict__ y,
                 float* __restrict__ out) {
    __shared__ float sm[C][2][LSZ];     // 32640 B
    __shared__ float4 red[2][256];      //  8192 B

    const int tid   = threadIdx.x;
    const int g     = tid >> 8;         // channel group 0..2 (wave-uniform)
    const int local = tid & 255;
    const int tx    = local & 15;       // 16 thread-cols x 4 px = 64 cols
    const int ty    = local >> 4;       // 16 rows
    const int w0    = blockIdx.x * TW;
    const int h0    = blockIdx.y * TH;
    const int b     = blockIdx.z;

    const float EPS = 1e-4f;

    // ---- each group stages its channel's x,y tiles ----
    {
        const float* __restrict__ xb = x + (size_t)(b * C + g) * (H * W);
        const float* __restrict__ yb = y + (size_t)(b * C + g) * (H * W);
        float* dX = &sm[g][0][0];
        float* dY = &sm[g][1][0];
        for (int i = local; i < LSZ; i += 256) {
            const int l  = i / LW;
            const int m  = i - l * LW;
            const int gr = h0 + l - HALO;
            const int gc = w0 + m - HALO;
            const bool ok = ((unsigned)gr < (unsigned)H) && ((unsigned)gc < (unsigned)W);
            const int gi = gr * W + gc;
            dX[i] = ok ? xb[gi] : 0.f;
            dY[i] = ok ? yb[gi] : 0.f;
        }
    }
    __syncthreads();

    const float* bx = &sm[g][0][0];
    const float* by = &sm[g][1][0];

    // ---- pass A: 5x5 sums for my 4 pixels (sliding row sums) ----
    float sxs[4] = {0.f, 0.f, 0.f, 0.f};
    float sys[4] = {0.f, 0.f, 0.f, 0.f};
    #pragma unroll
    for (int r = 0; r < 5; ++r) {
        const int base = (ty + r) * LW + 4 * tx;
        const float4 a0 = *reinterpret_cast<const float4*>(&bx[base]);
        const float4 a1 = *reinterpret_cast<const float4*>(&bx[base + 4]);
        const float4 b0 = *reinterpret_cast<const float4*>(&by[base]);
        const float4 b1 = *reinterpret_cast<const float4*>(&by[base + 4]);
        const float rx[8] = {a0.x, a0.y, a0.z, a0.w, a1.x, a1.y, a1.z, a1.w};
        const float ry[8] = {b0.x, b0.y, b0.z, b0.w, b1.x, b1.y, b1.z, b1.w};
        float s = rx[0] + rx[1] + rx[2] + rx[3] + rx[4];
        sxs[0] += s; s += rx[5] - rx[0];
        sxs[1] += s; s += rx[6] - rx[1];
        sxs[2] += s; s += rx[7] - rx[2];
        sxs[3] += s;
        float t = ry[0] + ry[1] + ry[2] + ry[3] + ry[4];
        sys[0] += t; t += ry[5] - ry[0];
        sys[1] += t; t += ry[6] - ry[1];
        sys[2] += t; t += ry[7] - ry[2];
        sys[3] += t;
    }
    float mx[4], my[4];
    #pragma unroll
    for (int p = 0; p < 4; ++p) {
        mx[p] = sxs[p] * (1.f / 25.f);
        my[p] = sys[p] * (1.f / 25.f);
    }

    // ---- pass B: ncc accumulation ----
    float acc[4] = {0.f, 0.f, 0.f, 0.f};
    #pragma unroll
    for (int r = 0; r < 5; ++r) {
        const int base = (ty + r) * LW + 4 * tx;
        const float4 a0 = *reinterpret_cast<const float4*>(&bx[base]);
        const float4 a1 = *reinterpret_cast<const float4*>(&bx[base + 4]);
        const float4 b0 = *reinterpret_cast<const float4*>(&by[base]);
        const float4 b1 = *reinterpret_cast<const float4*>(&by[base + 4]);
        const float rx[8] = {a0.x, a0.y, a0.z, a0.w, a1.x, a1.y, a1.z, a1.w};
        const float ry[8] = {b0.x, b0.y, b0.z, b0.w, b1.x, b1.y, b1.z, b1.w};
        #pragma unroll
        for (int p = 0; p < 4; ++p) {
            #pragma unroll
            for (int j = 0; j < 5; ++j) {
                const float dx  = rx[p + j] - mx[p];
                const float dy  = ry[p + j] - my[p];
                const float num = fabsf(dx * dy) + EPS;
                const float den = (dx * dx + EPS) * (dy * dy + EPS);
                acc[p] += num * __builtin_amdgcn_rsqf(den);
            }
        }
    }

    float4 mine;
    {
        float v0 = fminf(fmaxf(acc[0] * (1.f / 25.f), 0.f), 1.f);
        float v1 = fminf(fmaxf(acc[1] * (1.f / 25.f), 0.f), 1.f);
        float v2 = fminf(fmaxf(acc[2] * (1.f / 25.f), 0.f), 1.f);
        float v3 = fminf(fmaxf(acc[3] * (1.f / 25.f), 0.f), 1.f);
        mine = make_float4(v0, v1, v2, v3);
    }

    // ---- cross-group reduce: groups 1,2 post, group 0 combines + writes ----
    if (g > 0) red[g - 1][local] = mine;
    __syncthreads();

    if (g == 0) {
        const float4 r1 = red[0][local];
        const float4 r2 = red[1][local];
        const int orow = h0 + ty;
        float4 o;
        o.x = (mine.x + r1.x + r2.x) * (1.f / 3.f);
        o.y = (mine.y + r1.y + r2.y) * (1.f / 3.f);
        o.z = (mine.z + r1.z + r2.z) * (1.f / 3.f);
        o.w = (mine.w + r1.w + r2.w) * (1.f / 3.f);
        *reinterpret_cast<float4*>(&out[((size_t)b * H + orow) * W + w0 + 4 * tx]) = o;
    }
}

extern "C" void kernel_launch(void* const* d_in, const int* in_sizes, int n_in,
                              void* d_out, int out_size, void* d_ws, size_t ws_size,
                              hipStream_t stream) {
    const float* x = (const float*)d_in[0];
    const float* y = (const float*)d_in[1];
    float* out = (float*)d_out;
    dim3 grid(W / TW, H / TH, NB);   // 8, 32, 4 = 1024 blocks (2 resident/CU)
    zncc_kernel<<<grid, dim3(768), 0, stream>>>(x, y, out);
}